// Round 1
// baseline (1005.394 us; speedup 1.0000x reference)
//
#include <hip/hip_runtime.h>

#define BATCH 8
#define CIN 32
#define COUT 32
#define NK 4
#define HH 512
#define WW 512
#define EPSV 1e-8f

#define OCG 16      // output channels per conv block (COUT/2)
#define CICHUNK 8   // input channels staged per LDS chunk
#define SMW 35      // padded LDS row stride (34 used) -> <=2-way bank conflict

// ---------------------------------------------------------------------------
// Kernel 1: per-(b,oc) demodulated weights -> wt[b][oc][i][9]
// ---------------------------------------------------------------------------
__global__ __launch_bounds__(320) void prep_weights(
    const float* __restrict__ mod,         // [B, CIN]
    const float* __restrict__ kernel_mod,  // [B, NK]
    const float* __restrict__ weights,     // [NK, COUT, CIN, 3, 3]
    float* __restrict__ wt)                // [B, COUT, CIN*9]
{
    const int b  = blockIdx.x / COUT;
    const int oc = blockIdx.x % COUT;
    const int t  = threadIdx.x;            // 0..319, active < 288

    // softmax over kernel_mod[b, 0..3] (every thread computes it; 4 elems)
    const float k0 = kernel_mod[b * NK + 0];
    const float k1 = kernel_mod[b * NK + 1];
    const float k2 = kernel_mod[b * NK + 2];
    const float k3 = kernel_mod[b * NK + 3];
    const float mx = fmaxf(fmaxf(k0, k1), fmaxf(k2, k3));
    const float e0 = expf(k0 - mx), e1 = expf(k1 - mx);
    const float e2 = expf(k2 - mx), e3 = expf(k3 - mx);
    const float inv_s = 1.0f / (e0 + e1 + e2 + e3);
    const float a0 = e0 * inv_s, a1 = e1 * inv_s, a2 = e2 * inv_s, a3 = e3 * inv_s;

    float w = 0.0f;
    if (t < CIN * 9) {
        const int i = t / 9;
        const int base = (oc * CIN + i) * 9 + (t % 9);
        const int nstride = COUT * CIN * 9;
        w = a0 * weights[base]
          + a1 * weights[base + nstride]
          + a2 * weights[base + 2 * nstride]
          + a3 * weights[base + 3 * nstride];
        w *= (mod[b * CIN + i] + 1.0f);
    }

    // block reduction of sum(w^2) across 5 waves (inactive lanes contribute 0)
    float s = w * w;
    #pragma unroll
    for (int off = 1; off < 64; off <<= 1) s += __shfl_xor(s, off);
    __shared__ float red[5];
    const int wid = t >> 6, lane = t & 63;
    if (lane == 0) red[wid] = s;
    __syncthreads();
    const float tot = red[0] + red[1] + red[2] + red[3] + red[4];
    const float inv_norm = rsqrtf(fmaxf(tot, EPSV));

    if (t < CIN * 9) wt[(b * COUT + oc) * (CIN * 9) + t] = w * inv_norm;
}

// ---------------------------------------------------------------------------
// Kernel 2: direct conv. block = 256 thr, one (b, oc-group, 32x32 tile).
// LDS-stage fmap in 8-channel chunks; 4 px x 16 oc register blocking.
// Weights are block-uniform -> scalar loads.
// ---------------------------------------------------------------------------
__global__ __launch_bounds__(256) void conv_kernel(
    const float* __restrict__ fmap,  // [B, CIN, H, W]
    const float* __restrict__ wt,    // [B, COUT, CIN*9]
    float* __restrict__ out)         // [B, COUT, H, W]
{
    __shared__ float smem[CICHUNK][34][SMW];

    const int x0  = blockIdx.x * 32;
    const int y0  = blockIdx.y * 32;
    const int b   = blockIdx.z >> 1;
    const int ocg = blockIdx.z & 1;

    const int t    = threadIdx.x;
    const int row  = t >> 3;          // 0..31
    const int col4 = (t & 7) * 4;     // 0,4,...,28

    float acc[OCG][4];
    #pragma unroll
    for (int oc = 0; oc < OCG; ++oc)
        #pragma unroll
        for (int px = 0; px < 4; ++px) acc[oc][px] = 0.0f;

    for (int ci0 = 0; ci0 < CIN; ci0 += CICHUNK) {
        // cooperative stage: CICHUNK x 34 x 34 elements, zero-padded halo
        for (int idx = t; idx < CICHUNK * 34 * 34; idx += 256) {
            const int c = idx / (34 * 34);
            const int r = (idx % (34 * 34)) / 34;
            const int x = idx % 34;
            const int gy = y0 + r - 1;
            const int gx = x0 + x - 1;
            float v = 0.0f;
            if (gy >= 0 && gy < HH && gx >= 0 && gx < WW)
                v = fmap[((b * CIN + ci0 + c) * HH + gy) * WW + gx];
            smem[c][r][x] = v;
        }
        __syncthreads();

        #pragma unroll
        for (int i = 0; i < CICHUNK; ++i) {
            float f[3][6];
            #pragma unroll
            for (int dy = 0; dy < 3; ++dy)
                #pragma unroll
                for (int dx = 0; dx < 6; ++dx)
                    f[dy][dx] = smem[i][row + dy][col4 + dx];

            const float* wp = wt + ((b * COUT + ocg * OCG) * CIN + (ci0 + i)) * 9;
            #pragma unroll
            for (int oc = 0; oc < OCG; ++oc) {
                const float* wo = wp + oc * CIN * 9;
                #pragma unroll
                for (int dy = 0; dy < 3; ++dy)
                    #pragma unroll
                    for (int dx = 0; dx < 3; ++dx) {
                        const float wv = wo[dy * 3 + dx];
                        #pragma unroll
                        for (int px = 0; px < 4; ++px)
                            acc[oc][px] = fmaf(f[dy][px + dx], wv, acc[oc][px]);
                    }
            }
        }
        __syncthreads();
    }

    const int gy  = y0 + row;
    const int gx0 = x0 + col4;
    #pragma unroll
    for (int oc = 0; oc < OCG; ++oc) {
        float4 v = make_float4(acc[oc][0], acc[oc][1], acc[oc][2], acc[oc][3]);
        *reinterpret_cast<float4*>(
            &out[((b * COUT + ocg * OCG + oc) * HH + gy) * WW + gx0]) = v;
    }
}

// ---------------------------------------------------------------------------
extern "C" void kernel_launch(void* const* d_in, const int* in_sizes, int n_in,
                              void* d_out, int out_size, void* d_ws, size_t ws_size,
                              hipStream_t stream) {
    const float* fmap       = (const float*)d_in[0];
    const float* mod        = (const float*)d_in[1];
    const float* kernel_mod = (const float*)d_in[2];
    const float* weights    = (const float*)d_in[3];
    float* out = (float*)d_out;
    float* wt  = (float*)d_ws;   // [B][COUT][CIN*9] = 294,912 bytes

    prep_weights<<<dim3(BATCH * COUT), dim3(320), 0, stream>>>(
        mod, kernel_mod, weights, wt);

    conv_kernel<<<dim3(WW / 32, HH / 32, BATCH * 2), dim3(256), 0, stream>>>(
        fmap, wt, out);
}

// Round 2
// 320.053 us; speedup vs baseline: 3.1413x; 3.1413x over previous
//
#include <hip/hip_runtime.h>
#include <hip/hip_bf16.h>

#define BATCH 8
#define CIN 32
#define COUT 32
#define NK 4
#define HH 512
#define WW 512
#define HW (HH*WW)
#define EPSV 1e-8f

typedef __attribute__((ext_vector_type(8))) short short8;   // bf16 MFMA frag (4 VGPR)
typedef __attribute__((ext_vector_type(16))) float f32x16;  // 32x32 accumulator

// ---------------------------------------------------------------------------
// Kernel 1: mixed+modulated+demodulated weights -> bf16 wt[b][oc][k], k=tap*32+ci
// ---------------------------------------------------------------------------
__global__ __launch_bounds__(320) void prep_weights(
    const float* __restrict__ mod,         // [B, CIN]
    const float* __restrict__ kernel_mod,  // [B, NK]
    const float* __restrict__ weights,     // [NK, COUT, CIN, 3, 3]
    unsigned short* __restrict__ wtb)      // [B, COUT, 288] bf16
{
    const int b  = blockIdx.x / COUT;
    const int oc = blockIdx.x % COUT;
    const int t  = threadIdx.x;            // 0..319, active < 288

    const float k0 = kernel_mod[b * NK + 0];
    const float k1 = kernel_mod[b * NK + 1];
    const float k2 = kernel_mod[b * NK + 2];
    const float k3 = kernel_mod[b * NK + 3];
    const float mx = fmaxf(fmaxf(k0, k1), fmaxf(k2, k3));
    const float e0 = expf(k0 - mx), e1 = expf(k1 - mx);
    const float e2 = expf(k2 - mx), e3 = expf(k3 - mx);
    const float inv_s = 1.0f / (e0 + e1 + e2 + e3);
    const float a0 = e0 * inv_s, a1 = e1 * inv_s, a2 = e2 * inv_s, a3 = e3 * inv_s;

    float w = 0.0f;
    int i = 0, tap = 0;
    if (t < CIN * 9) {
        i   = t / 9;
        tap = t % 9;
        const int base = (oc * CIN + i) * 9 + tap;
        const int nstride = COUT * CIN * 9;
        w = a0 * weights[base]
          + a1 * weights[base + nstride]
          + a2 * weights[base + 2 * nstride]
          + a3 * weights[base + 3 * nstride];
        w *= (mod[b * CIN + i] + 1.0f);
    }

    float s = w * w;
    #pragma unroll
    for (int off = 1; off < 64; off <<= 1) s += __shfl_xor(s, off);
    __shared__ float red[5];
    const int wid = t >> 6, lane = t & 63;
    if (lane == 0) red[wid] = s;
    __syncthreads();
    const float tot = red[0] + red[1] + red[2] + red[3] + red[4];
    const float inv_norm = rsqrtf(fmaxf(tot, EPSV));

    if (t < CIN * 9) {
        __hip_bfloat16 h = __float2bfloat16(w * inv_norm);
        // k-ordering: k = tap*32 + ci  (ci fastest within 16B frag reads)
        wtb[(b * COUT + oc) * 288 + tap * CIN + i] =
            *reinterpret_cast<unsigned short*>(&h);
    }
}

// ---------------------------------------------------------------------------
// Kernel 2: implicit-GEMM conv via mfma_f32_32x32x16_bf16.
// Block: 256 thr (4 waves), one (b, 16-row x 32-px tile).
// LDS: NHWC bf16 tile [18 rows][34 x][32 ci], XOR-swizzled 16B chunks.
// Each wave computes 4 row-tiles of 32 oc x 32 px, K=288 in 18 MFMA steps.
// ---------------------------------------------------------------------------
#define ROWS 16
#define XW 32
#define SR (ROWS + 2)   // 18
#define SX (XW + 2)     // 34
#define NPIX (SR * SX)  // 612

__global__ __launch_bounds__(256) void conv_mfma(
    const float* __restrict__ fmap,           // [B, CIN, H, W] f32
    const unsigned short* __restrict__ wtb,   // [B, COUT, 288] bf16
    float* __restrict__ out)                  // [B, COUT, H, W] f32
{
    __shared__ short8 lds[NPIX * 4];          // 39,168 B

    const int x0 = blockIdx.x * XW;
    const int y0 = blockIdx.y * ROWS;
    const int b  = blockIdx.z;

    const int t    = threadIdx.x;
    const int lane = t & 63;
    const int wid  = t >> 6;
    const int oc   = lane & 31;
    const int half = lane >> 5;

    // ---- A fragments: weights for this batch, all 18 K-steps, in registers ----
    short8 afrag[18];
    {
        const unsigned short* wp = wtb + (b * COUT + oc) * 288 + half * 8;
        #pragma unroll
        for (int s = 0; s < 18; ++s)
            afrag[s] = *reinterpret_cast<const short8*>(wp + s * 16);
    }

    // ---- stage fmap tile: f32 NCHW global -> bf16 NHWC LDS (swizzled) ----
    for (int p = t; p < NPIX; p += 256) {
        const int r  = p / SX;
        const int xx = p - r * SX;
        const int gy = y0 + r - 1;
        const int gx = x0 + xx - 1;
        const bool ok = (gy >= 0) && (gy < HH) && (gx >= 0) && (gx < WW);
        const int base = (b * CIN) * HW + gy * WW + gx;   // valid only if ok
        const int sw = (xx >> 1) & 3;
        #pragma unroll
        for (int cb = 0; cb < 4; ++cb) {
            short8 sv;
            #pragma unroll
            for (int j = 0; j < 8; ++j) {
                float f = 0.0f;
                if (ok) f = fmap[base + (cb * 8 + j) * HW];
                __hip_bfloat16 h = __float2bfloat16(f);
                sv[j] = *reinterpret_cast<short*>(&h);
            }
            lds[p * 4 + (cb ^ sw)] = sv;
        }
    }
    __syncthreads();

    // ---- compute: each wave does row-tiles wid, wid+4, wid+8, wid+12 ----
    const int col = lane & 31;   // output x within tile
    #pragma unroll
    for (int ti = 0; ti < 4; ++ti) {
        const int yloc = wid + ti * 4;
        f32x16 acc;
        #pragma unroll
        for (int reg = 0; reg < 16; ++reg) acc[reg] = 0.0f;

        #pragma unroll
        for (int s = 0; s < 18; ++s) {
            const int tap = s >> 1;          // 0..8
            const int dy  = tap / 3;         // compile-time per unrolled s
            const int dx  = tap % 3;
            const int r   = yloc + dy;       // 0..17
            const int xx  = col + dx;        // 0..33
            const int c   = ((s & 1) << 1) | half;          // 16B chunk (8 ci)
            const int ch  = (r * SX + xx) * 4 + (c ^ ((xx >> 1) & 3));
            const short8 bfrag = lds[ch];
            acc = __builtin_amdgcn_mfma_f32_32x32x16_bf16(afrag[s], bfrag, acc, 0, 0, 0);
        }

        // C/D layout (verified m74/m101): col = lane&31, row = (reg&3)+8*(reg>>2)+4*half
        const int gy = y0 + yloc;
        float* op = out + (b * COUT) * HW + gy * WW + x0 + col;
        #pragma unroll
        for (int reg = 0; reg < 16; ++reg) {
            const int oc_o = (reg & 3) + 8 * (reg >> 2) + 4 * half;
            op[oc_o * HW] = acc[reg];
        }
    }
}

// ---------------------------------------------------------------------------
extern "C" void kernel_launch(void* const* d_in, const int* in_sizes, int n_in,
                              void* d_out, int out_size, void* d_ws, size_t ws_size,
                              hipStream_t stream) {
    const float* fmap       = (const float*)d_in[0];
    const float* mod        = (const float*)d_in[1];
    const float* kernel_mod = (const float*)d_in[2];
    const float* weights    = (const float*)d_in[3];
    float* out = (float*)d_out;
    unsigned short* wtb = (unsigned short*)d_ws;   // [8][32][288] bf16 = 147,456 B

    prep_weights<<<dim3(BATCH * COUT), dim3(320), 0, stream>>>(
        mod, kernel_mod, weights, wtb);

    conv_mfma<<<dim3(WW / XW, HH / ROWS, BATCH), dim3(256), 0, stream>>>(
        fmap, wtb, out);
}

// Round 3
// 204.722 us; speedup vs baseline: 4.9110x; 1.5634x over previous
//
#include <hip/hip_runtime.h>
#include <hip/hip_bf16.h>

#define BATCH 8
#define CIN 32
#define COUT 32
#define NK 4
#define HH 512
#define WW 512
#define HW (HH*WW)
#define EPSV 1e-8f

typedef __attribute__((ext_vector_type(8))) short short8;   // bf16 MFMA frag (4 VGPR)
typedef __attribute__((ext_vector_type(16))) float f32x16;  // 32x32 accumulator

static __device__ __forceinline__ unsigned short to_bf16(float f) {
    __hip_bfloat16 h = __float2bfloat16(f);
    return *reinterpret_cast<unsigned short*>(&h);
}

// ---------------------------------------------------------------------------
// Kernel 1: mixed+modulated+demodulated weights -> bf16 wt[b][oc][k], k=tap*32+ci
// ---------------------------------------------------------------------------
__global__ __launch_bounds__(320) void prep_weights(
    const float* __restrict__ mod,         // [B, CIN]
    const float* __restrict__ kernel_mod,  // [B, NK]
    const float* __restrict__ weights,     // [NK, COUT, CIN, 3, 3]
    unsigned short* __restrict__ wtb)      // [B, COUT, 288] bf16
{
    const int b  = blockIdx.x / COUT;
    const int oc = blockIdx.x % COUT;
    const int t  = threadIdx.x;            // 0..319, active < 288

    const float k0 = kernel_mod[b * NK + 0];
    const float k1 = kernel_mod[b * NK + 1];
    const float k2 = kernel_mod[b * NK + 2];
    const float k3 = kernel_mod[b * NK + 3];
    const float mx = fmaxf(fmaxf(k0, k1), fmaxf(k2, k3));
    const float e0 = expf(k0 - mx), e1 = expf(k1 - mx);
    const float e2 = expf(k2 - mx), e3 = expf(k3 - mx);
    const float inv_s = 1.0f / (e0 + e1 + e2 + e3);
    const float a0 = e0 * inv_s, a1 = e1 * inv_s, a2 = e2 * inv_s, a3 = e3 * inv_s;

    float w = 0.0f;
    int i = 0, tap = 0;
    if (t < CIN * 9) {
        i   = t / 9;
        tap = t % 9;
        const int base = (oc * CIN + i) * 9 + tap;
        const int nstride = COUT * CIN * 9;
        w = a0 * weights[base]
          + a1 * weights[base + nstride]
          + a2 * weights[base + 2 * nstride]
          + a3 * weights[base + 3 * nstride];
        w *= (mod[b * CIN + i] + 1.0f);
    }

    float s = w * w;
    #pragma unroll
    for (int off = 1; off < 64; off <<= 1) s += __shfl_xor(s, off);
    __shared__ float red[5];
    const int wid = t >> 6, lane = t & 63;
    if (lane == 0) red[wid] = s;
    __syncthreads();
    const float tot = red[0] + red[1] + red[2] + red[3] + red[4];
    const float inv_norm = rsqrtf(fmaxf(tot, EPSV));

    if (t < CIN * 9)
        wtb[(b * COUT + oc) * 288 + tap * CIN + i] = to_bf16(w * inv_norm);
}

// ---------------------------------------------------------------------------
// Kernel T: transpose [B,32,H,W] f32 -> [B,H,W,32] bf16.
// Block = 256 thr = one row-segment of 256 px, all 32 ch.
// LDS 16KB, word-level XOR swizzle (pos = c2 ^ (px & 12)) -> b128-readable,
// <=4-way write / 2-way read conflicts.
// ---------------------------------------------------------------------------
#define TPX 256
__global__ __launch_bounds__(256) void transpose_to_nhwc(
    const float* __restrict__ fmap,      // [B,32,H,W] f32
    unsigned short* __restrict__ fbf)    // [B,H,W,32] bf16
{
    __shared__ unsigned int sm[TPX * 16];   // 16 KB (16 words = 32 bf16 per px)
    const int x0 = blockIdx.x * TPX;
    const int y  = blockIdx.y;
    const int b  = blockIdx.z;
    const int t  = threadIdx.x;

    const float* fp = fmap + ((size_t)(b * CIN) * HH + y) * WW + x0 + t;
    #pragma unroll
    for (int c2 = 0; c2 < 16; ++c2) {
        const float f0 = fp[(size_t)(2 * c2) * HW];
        const float f1 = fp[(size_t)(2 * c2 + 1) * HW];
        const unsigned int pk = (unsigned int)to_bf16(f0)
                              | ((unsigned int)to_bf16(f1) << 16);
        sm[t * 16 + (c2 ^ (t & 12))] = pk;
    }
    __syncthreads();

    unsigned short* op = fbf + ((size_t)(b * HH + y) * WW + x0) * 32;
    #pragma unroll
    for (int k = 0; k < 4; ++k) {
        const int idx = t + 256 * k;         // 16B chunk id, 0..1023
        const int p   = idx >> 2;            // pixel 0..255
        const int chb = idx & 3;             // which 16B of the 64B pixel
        const unsigned int* sp = sm + p * 16 + ((4 * chb) ^ (p & 12));
        uint4 v;
        v.x = sp[0]; v.y = sp[1]; v.z = sp[2]; v.w = sp[3];
        *reinterpret_cast<uint4*>(op + (size_t)idx * 8) = v;
    }
}

// ---------------------------------------------------------------------------
// Kernel 2: implicit-GEMM conv, NHWC bf16 input.
// Block: 256 thr (4 waves), tile 16 rows x 32 px, one batch.
// LDS transposed layout: [chunk c(8ci)][612 px][16B] -> conflict-free b128
// reads (lanes hit consecutive 16B slots) and writes.
// Wave w stages chunk c=w; compute = 4 row-tiles x 18 MFMA (32x32x16 bf16).
// ---------------------------------------------------------------------------
#define ROWS 16
#define XW 32
#define SR (ROWS + 2)   // 18
#define SX (XW + 2)     // 34
#define NPIX (SR * SX)  // 612

__global__ __launch_bounds__(256) void conv_mfma_nhwc(
    const unsigned short* __restrict__ fbf,   // [B,H,W,32] bf16
    const unsigned short* __restrict__ wtb,   // [B, COUT, 288] bf16
    float* __restrict__ out)                  // [B, COUT, H, W] f32
{
    __shared__ short8 lds[4 * NPIX];          // 39,168 B

    const int x0   = blockIdx.x * XW;
    const int y0   = blockIdx.y * ROWS;
    const int b    = blockIdx.z;
    const int t    = threadIdx.x;
    const int lane = t & 63;
    const int wid  = t >> 6;
    const int oc   = lane & 31;
    const int half = lane >> 5;

    // A fragments: weights for this batch, all 18 K-steps (L2-hot, 147KB)
    short8 afrag[18];
    {
        const unsigned short* wp = wtb + (b * COUT + oc) * 288 + half * 8;
        #pragma unroll
        for (int s = 0; s < 18; ++s)
            afrag[s] = *reinterpret_cast<const short8*>(wp + s * 16);
    }

    // ---- stage: wave `wid` owns chunk c = wid; pixels p = lane + 64j ----
    const unsigned short* fb = fbf + (size_t)b * (HW * 32);
    #pragma unroll
    for (int j = 0; j < 10; ++j) {
        const int p = lane + 64 * j;
        if (p < NPIX) {
            const int r  = (p * 3856) >> 17;      // p / 34  (exact for p < 612)
            const int xx = p - 34 * r;
            const int gy = y0 + r - 1;
            const int gx = x0 + xx - 1;
            short8 v;
            #pragma unroll
            for (int q = 0; q < 8; ++q) v[q] = 0;
            if (gy >= 0 && gy < HH && gx >= 0 && gx < WW)
                v = *reinterpret_cast<const short8*>(fb + ((gy * WW + gx) * 32 + wid * 8));
            lds[wid * NPIX + p] = v;
        }
    }
    __syncthreads();

    // ---- compute: each wave does row-tiles wid, wid+4, wid+8, wid+12 ----
    const int col = lane & 31;
    #pragma unroll
    for (int ti = 0; ti < 4; ++ti) {
        const int yloc = wid + ti * 4;
        f32x16 acc;
        #pragma unroll
        for (int reg = 0; reg < 16; ++reg) acc[reg] = 0.0f;

        #pragma unroll
        for (int s = 0; s < 18; ++s) {
            const int tap = s >> 1;              // 0..8
            const int dy  = tap / 3;
            const int dx  = tap % 3;
            const int c   = ((s & 1) << 1) | half;           // 16B chunk (8 ci)
            const int idx = c * NPIX + (yloc + dy) * SX + col + dx;
            const short8 bfrag = lds[idx];
            acc = __builtin_amdgcn_mfma_f32_32x32x16_bf16(afrag[s], bfrag, acc, 0, 0, 0);
        }

        // C/D layout (verified m74/m101): col = lane&31, row = (reg&3)+8*(reg>>2)+4*half
        const int gy = y0 + yloc;
        float* op = out + (b * COUT) * HW + gy * WW + x0 + col;
        #pragma unroll
        for (int reg = 0; reg < 16; ++reg) {
            const int oc_o = (reg & 3) + 8 * (reg >> 2) + 4 * half;
            op[oc_o * HW] = acc[reg];
        }
    }
}

// ---------------------------------------------------------------------------
// Fallback conv (round-2 kernel): f32 NCHW staging, used only if ws too small.
// ---------------------------------------------------------------------------
__global__ __launch_bounds__(256) void conv_mfma_nchw(
    const float* __restrict__ fmap,
    const unsigned short* __restrict__ wtb,
    float* __restrict__ out)
{
    __shared__ short8 lds[NPIX * 4];

    const int x0 = blockIdx.x * XW;
    const int y0 = blockIdx.y * ROWS;
    const int b  = blockIdx.z;
    const int t    = threadIdx.x;
    const int lane = t & 63;
    const int wid  = t >> 6;
    const int oc   = lane & 31;
    const int half = lane >> 5;

    short8 afrag[18];
    {
        const unsigned short* wp = wtb + (b * COUT + oc) * 288 + half * 8;
        #pragma unroll
        for (int s = 0; s < 18; ++s)
            afrag[s] = *reinterpret_cast<const short8*>(wp + s * 16);
    }

    for (int p = t; p < NPIX; p += 256) {
        const int r  = p / SX;
        const int xx = p - r * SX;
        const int gy = y0 + r - 1;
        const int gx = x0 + xx - 1;
        const bool ok = (gy >= 0) && (gy < HH) && (gx >= 0) && (gx < WW);
        const int base = (b * CIN) * HW + gy * WW + gx;
        #pragma unroll
        for (int cb = 0; cb < 4; ++cb) {
            short8 sv;
            #pragma unroll
            for (int q = 0; q < 8; ++q) {
                float f = 0.0f;
                if (ok) f = fmap[base + (cb * 8 + q) * HW];
                sv[q] = (short)to_bf16(f);
            }
            lds[cb * NPIX + p] = sv;
        }
    }
    __syncthreads();

    const int col = lane & 31;
    #pragma unroll
    for (int ti = 0; ti < 4; ++ti) {
        const int yloc = wid + ti * 4;
        f32x16 acc;
        #pragma unroll
        for (int reg = 0; reg < 16; ++reg) acc[reg] = 0.0f;
        #pragma unroll
        for (int s = 0; s < 18; ++s) {
            const int tap = s >> 1;
            const int dy  = tap / 3;
            const int dx  = tap % 3;
            const int c   = ((s & 1) << 1) | half;
            const int idx = c * NPIX + (yloc + dy) * SX + col + dx;
            const short8 bfrag = lds[idx];
            acc = __builtin_amdgcn_mfma_f32_32x32x16_bf16(afrag[s], bfrag, acc, 0, 0, 0);
        }
        const int gy = y0 + yloc;
        float* op = out + (b * COUT) * HW + gy * WW + x0 + col;
        #pragma unroll
        for (int reg = 0; reg < 16; ++reg) {
            const int oc_o = (reg & 3) + 8 * (reg >> 2) + 4 * half;
            op[oc_o * HW] = acc[reg];
        }
    }
}

// ---------------------------------------------------------------------------
extern "C" void kernel_launch(void* const* d_in, const int* in_sizes, int n_in,
                              void* d_out, int out_size, void* d_ws, size_t ws_size,
                              hipStream_t stream) {
    const float* fmap       = (const float*)d_in[0];
    const float* mod        = (const float*)d_in[1];
    const float* kernel_mod = (const float*)d_in[2];
    const float* weights    = (const float*)d_in[3];
    float* out = (float*)d_out;

    unsigned short* wtb = (unsigned short*)d_ws;            // 147,456 B
    unsigned short* fbf = (unsigned short*)((char*)d_ws + 147456);
    const size_t need = 147456 + (size_t)BATCH * HW * 32 * 2;  // 134,365,184 B

    prep_weights<<<dim3(BATCH * COUT), dim3(320), 0, stream>>>(
        mod, kernel_mod, weights, wtb);

    if (ws_size >= need) {
        transpose_to_nhwc<<<dim3(WW / TPX, HH, BATCH), dim3(256), 0, stream>>>(
            fmap, fbf);
        conv_mfma_nhwc<<<dim3(WW / XW, HH / ROWS, BATCH), dim3(256), 0, stream>>>(
            fbf, wtb, out);
    } else {
        conv_mfma_nchw<<<dim3(WW / XW, HH / ROWS, BATCH), dim3(256), 0, stream>>>(
            fmap, wtb, out);
    }
}

// Round 4
// 168.308 us; speedup vs baseline: 5.9735x; 1.2164x over previous
//
#include <hip/hip_runtime.h>
#include <hip/hip_bf16.h>

#define BATCH 8
#define CIN 32
#define COUT 32
#define NK 4
#define HH 512
#define WW 512
#define HW (HH*WW)
#define EPSV 1e-8f

typedef __attribute__((ext_vector_type(8))) short short8;   // bf16 MFMA frag (4 VGPR)
typedef __attribute__((ext_vector_type(16))) float f32x16;  // 32x32 accumulator

static __device__ __forceinline__ unsigned short to_bf16(float f) {
    __hip_bfloat16 h = __float2bfloat16(f);
    return *reinterpret_cast<unsigned short*>(&h);
}

// ---------------------------------------------------------------------------
// Kernel 1: mixed+modulated+demodulated weights -> bf16 wt[b][oc][k], k=tap*32+ci
// ---------------------------------------------------------------------------
__global__ __launch_bounds__(320) void prep_weights(
    const float* __restrict__ mod,         // [B, CIN]
    const float* __restrict__ kernel_mod,  // [B, NK]
    const float* __restrict__ weights,     // [NK, COUT, CIN, 3, 3]
    unsigned short* __restrict__ wtb)      // [B, COUT, 288] bf16
{
    const int b  = blockIdx.x / COUT;
    const int oc = blockIdx.x % COUT;
    const int t  = threadIdx.x;            // 0..319, active < 288

    const float k0 = kernel_mod[b * NK + 0];
    const float k1 = kernel_mod[b * NK + 1];
    const float k2 = kernel_mod[b * NK + 2];
    const float k3 = kernel_mod[b * NK + 3];
    const float mx = fmaxf(fmaxf(k0, k1), fmaxf(k2, k3));
    const float e0 = expf(k0 - mx), e1 = expf(k1 - mx);
    const float e2 = expf(k2 - mx), e3 = expf(k3 - mx);
    const float inv_s = 1.0f / (e0 + e1 + e2 + e3);
    const float a0 = e0 * inv_s, a1 = e1 * inv_s, a2 = e2 * inv_s, a3 = e3 * inv_s;

    float w = 0.0f;
    int i = 0, tap = 0;
    if (t < CIN * 9) {
        i   = t / 9;
        tap = t % 9;
        const int base = (oc * CIN + i) * 9 + tap;
        const int nstride = COUT * CIN * 9;
        w = a0 * weights[base]
          + a1 * weights[base + nstride]
          + a2 * weights[base + 2 * nstride]
          + a3 * weights[base + 3 * nstride];
        w *= (mod[b * CIN + i] + 1.0f);
    }

    float s = w * w;
    #pragma unroll
    for (int off = 1; off < 64; off <<= 1) s += __shfl_xor(s, off);
    __shared__ float red[5];
    const int wid = t >> 6, lane = t & 63;
    if (lane == 0) red[wid] = s;
    __syncthreads();
    const float tot = red[0] + red[1] + red[2] + red[3] + red[4];
    const float inv_norm = rsqrtf(fmaxf(tot, EPSV));

    if (t < CIN * 9)
        wtb[(b * COUT + oc) * 288 + tap * CIN + i] = to_bf16(w * inv_norm);
}

// ---------------------------------------------------------------------------
// Kernel 2 (fused): implicit-GEMM conv straight from f32 NCHW fmap.
// Block: 256 thr (4 waves), tile 16 rows x 32 px, one batch slice.
// Stage: per-(chunk,pixel) gather of 8 channels (px-coalesced 256B segments),
// cvt to bf16, pack 16B, write to conflict-free LDS [chunk][612][16B].
// XCD swizzle: b = n&7 pins each batch to one XCD -> halo lines stay L2-hot.
// Compute: per wave 4 row-tiles x 18 x mfma_f32_32x32x16_bf16.
// ---------------------------------------------------------------------------
#define ROWS 16
#define XW 32
#define SR (ROWS + 2)   // 18
#define SX (XW + 2)     // 34
#define NPIX (SR * SX)  // 612

__global__ __launch_bounds__(256) void conv_fused(
    const float* __restrict__ fmap,           // [B, CIN, H, W] f32
    const unsigned short* __restrict__ wtb,   // [B, COUT, 288] bf16
    float* __restrict__ out)                  // [B, COUT, H, W] f32
{
    __shared__ short8 lds[4 * NPIX];          // 39,168 B -> 4 blocks/CU

    // XCD-pinned decomposition: XCD (n&7) owns batch b, sweeps tiles row-major
    const int n  = blockIdx.x;
    const int b  = n & 7;
    const int m  = n >> 3;
    const int x0 = (m & 15) * XW;             // 16 x-tiles
    const int y0 = (m >> 4) * ROWS;           // 32 y-tiles

    const int t    = threadIdx.x;
    const int lane = t & 63;
    const int wid  = t >> 6;
    const int oc   = lane & 31;
    const int half = lane >> 5;

    // A fragments: weights for this batch (147KB total -> L2-hot)
    short8 afrag[18];
    {
        const unsigned short* wp = wtb + (b * COUT + oc) * 288 + half * 8;
        #pragma unroll
        for (int s = 0; s < 18; ++s)
            afrag[s] = *reinterpret_cast<const short8*>(wp + s * 16);
    }

    // ---- stage: f32 NCHW -> bf16 chunked LDS, statically unrolled ----
    const float* fb = fmap + (size_t)b * CIN * HW;
    #pragma unroll
    for (int j = 0; j < 10; ++j) {
        const int idx = t + j * 256;          // 0..2447 (4 chunks x 612 px)
        if (idx < 4 * NPIX) {
            const int cb = idx / NPIX;
            const int p  = idx - cb * NPIX;
            const int r  = (p * 3856) >> 17;  // p / 34 (exact for p < 612)
            const int xx = p - SX * r;
            const int gy = y0 + r - 1;
            const int gx = x0 + xx - 1;
            short8 v;
            #pragma unroll
            for (int q = 0; q < 8; ++q) v[q] = 0;
            if (gy >= 0 && gy < HH && gx >= 0 && gx < WW) {
                const float* src = fb + (size_t)(cb * 8) * HW + gy * WW + gx;
                #pragma unroll
                for (int q = 0; q < 8; ++q)
                    v[q] = (short)to_bf16(src[(size_t)q * HW]);
            }
            lds[cb * NPIX + p] = v;           // lanes -> consecutive 16B: conflict-free
        }
    }
    __syncthreads();

    // ---- compute: each wave does row-tiles wid, wid+4, wid+8, wid+12 ----
    const int col = lane & 31;
    #pragma unroll
    for (int ti = 0; ti < 4; ++ti) {
        const int yloc = wid + ti * 4;
        f32x16 acc;
        #pragma unroll
        for (int reg = 0; reg < 16; ++reg) acc[reg] = 0.0f;

        #pragma unroll
        for (int s = 0; s < 18; ++s) {
            const int tap = s >> 1;              // 0..8
            const int dy  = tap / 3;
            const int dx  = tap % 3;
            const int c   = ((s & 1) << 1) | half;           // 16B chunk (8 ci)
            const int idx = c * NPIX + (yloc + dy) * SX + col + dx;
            const short8 bfrag = lds[idx];
            acc = __builtin_amdgcn_mfma_f32_32x32x16_bf16(afrag[s], bfrag, acc, 0, 0, 0);
        }

        // C/D layout (verified m74/m101): col = lane&31, row = (reg&3)+8*(reg>>2)+4*half
        const int gy = y0 + yloc;
        float* op = out + (b * COUT) * HW + gy * WW + x0 + col;
        #pragma unroll
        for (int reg = 0; reg < 16; ++reg) {
            const int oc_o = (reg & 3) + 8 * (reg >> 2) + 4 * half;
            op[oc_o * HW] = acc[reg];
        }
    }
}

// ---------------------------------------------------------------------------
extern "C" void kernel_launch(void* const* d_in, const int* in_sizes, int n_in,
                              void* d_out, int out_size, void* d_ws, size_t ws_size,
                              hipStream_t stream) {
    const float* fmap       = (const float*)d_in[0];
    const float* mod        = (const float*)d_in[1];
    const float* kernel_mod = (const float*)d_in[2];
    const float* weights    = (const float*)d_in[3];
    float* out = (float*)d_out;
    unsigned short* wtb = (unsigned short*)d_ws;   // [8][32][288] bf16 = 147,456 B

    prep_weights<<<dim3(BATCH * COUT), dim3(320), 0, stream>>>(
        mod, kernel_mod, weights, wtb);

    conv_fused<<<dim3((WW / XW) * (HH / ROWS) * BATCH), dim3(256), 0, stream>>>(
        fmap, wtb, out);
}

// Round 5
// 113.943 us; speedup vs baseline: 8.8237x; 1.4771x over previous
//
#include <hip/hip_runtime.h>
#include <hip/hip_bf16.h>

#define BATCH 8
#define CIN 32
#define COUT 32
#define NK 4
#define HH 512
#define WW 512
#define HW (HH*WW)
#define EPSV 1e-8f

typedef __attribute__((ext_vector_type(8))) short short8;   // bf16 MFMA frag (4 VGPR)
typedef __attribute__((ext_vector_type(16))) float f32x16;  // 32x32 accumulator

static __device__ __forceinline__ unsigned short to_bf16(float f) {
    __hip_bfloat16 h = __float2bfloat16(f);
    return *reinterpret_cast<unsigned short*>(&h);
}

// ---------------------------------------------------------------------------
// Kernel 1: mixed+modulated+demodulated weights -> bf16 wt[b][oc][k], k=tap*32+ci
// ---------------------------------------------------------------------------
__global__ __launch_bounds__(320) void prep_weights(
    const float* __restrict__ mod,         // [B, CIN]
    const float* __restrict__ kernel_mod,  // [B, NK]
    const float* __restrict__ weights,     // [NK, COUT, CIN, 3, 3]
    unsigned short* __restrict__ wtb)      // [B, COUT, 288] bf16
{
    const int b  = blockIdx.x / COUT;
    const int oc = blockIdx.x % COUT;
    const int t  = threadIdx.x;            // 0..319, active < 288

    const float k0 = kernel_mod[b * NK + 0];
    const float k1 = kernel_mod[b * NK + 1];
    const float k2 = kernel_mod[b * NK + 2];
    const float k3 = kernel_mod[b * NK + 3];
    const float mx = fmaxf(fmaxf(k0, k1), fmaxf(k2, k3));
    const float e0 = expf(k0 - mx), e1 = expf(k1 - mx);
    const float e2 = expf(k2 - mx), e3 = expf(k3 - mx);
    const float inv_s = 1.0f / (e0 + e1 + e2 + e3);
    const float a0 = e0 * inv_s, a1 = e1 * inv_s, a2 = e2 * inv_s, a3 = e3 * inv_s;

    float w = 0.0f;
    int i = 0, tap = 0;
    if (t < CIN * 9) {
        i   = t / 9;
        tap = t % 9;
        const int base = (oc * CIN + i) * 9 + tap;
        const int nstride = COUT * CIN * 9;
        w = a0 * weights[base]
          + a1 * weights[base + nstride]
          + a2 * weights[base + 2 * nstride]
          + a3 * weights[base + 3 * nstride];
        w *= (mod[b * CIN + i] + 1.0f);
    }

    float s = w * w;
    #pragma unroll
    for (int off = 1; off < 64; off <<= 1) s += __shfl_xor(s, off);
    __shared__ float red[5];
    const int wid = t >> 6, lane = t & 63;
    if (lane == 0) red[wid] = s;
    __syncthreads();
    const float tot = red[0] + red[1] + red[2] + red[3] + red[4];
    const float inv_norm = rsqrtf(fmaxf(tot, EPSV));

    if (t < CIN * 9)
        wtb[(b * COUT + oc) * 288 + tap * CIN + i] = to_bf16(w * inv_norm);
}

// ---------------------------------------------------------------------------
// Kernel 2 (fused v2): implicit-GEMM conv from f32 NCHW fmap.
// Block: 512 thr (8 waves), tile 16 rows x 32 px, one batch slice.
// Staging: dense float4 loads (lane-pairs cover 2 channel planes -> 2x512B
// contiguous segments/instr), direct 2B LDS writes into interleaved
// [chunk(8ci)][slot][16B] layout. Slot-level XOR swizzle (involution) keeps
// writes <=4-way conflicted and b128 reads conflict-free.
// Slots per row: 0..35 = px gx=x0..x0+35 (quads), 36 = left halo gx=x0-1.
// Compute: wave w -> row-tiles (w, w+8); 18 x mfma_f32_32x32x16_bf16 each.
// ---------------------------------------------------------------------------
#define ROWS 16
#define XW 32
#define SR 18              // staged rows
#define SPR 37             // slots per row: 36 quad px + 1 left-halo
#define NSLOT (SR * SPR)   // 666
#define CH_STRIDE 668      // padded chunk stride (swizzle image <= 667)
#define QP 176             // padded quads per ci (162 real = 18 rows x 9)

static __device__ __forceinline__ int swz(int s) {
    return (s & ~3) | ((s ^ (s >> 2)) & 3);   // involution within quad groups
}

__global__ __launch_bounds__(512, 6) void conv_fused(
    const float* __restrict__ fmap,           // [B, CIN, H, W] f32
    const unsigned short* __restrict__ wtb,   // [B, COUT, 288] bf16
    float* __restrict__ out)                  // [B, COUT, H, W] f32
{
    __shared__ short8 lds[4 * CH_STRIDE];     // 42,752 B -> 3 blocks/CU

    // XCD-pinned decomposition: XCD (n&7) owns batch b, sweeps tiles row-major
    const int n  = blockIdx.x;
    const int b  = n & 7;
    const int m  = n >> 3;
    const int x0 = (m & 15) * XW;             // 16 x-tiles
    const int y0 = (m >> 4) * ROWS;           // 32 y-tiles

    const int t    = threadIdx.x;
    const int lane = t & 63;
    const int w    = t >> 6;                  // wave 0..7
    const int oc   = lane & 31;
    const int half = lane >> 5;

    unsigned short* ldsu = (unsigned short*)lds;
    const float* fb = fmap + (size_t)b * CIN * HW;

    // ---- P1: dense quad staging (32 ci x 162 quads) ----
    #pragma unroll
    for (int k = 0; k < 11; ++k) {
        const int u  = t + 512 * k;           // < 5632 = 32*QP, no guard needed
        const int pr = u >> 1;                // lane-pair id
        const int cp = pr / QP;               // ci-pair 0..15
        const int q  = pr - cp * QP;          // 0..175
        const int ci = cp * 2 + (u & 1);
        if (q < 162) {
            const int r  = q / 9;             // 0..17
            const int qq = q - r * 9;         // 0..8
            const int gy = y0 + r - 1;
            const int gx = x0 + qq * 4;       // 16B-aligned (x0 % 32 == 0)
            float4 v = make_float4(0.f, 0.f, 0.f, 0.f);
            if (gy >= 0 && gy < HH && gx + 3 < WW)
                v = *reinterpret_cast<const float4*>(
                        fb + (size_t)ci * HW + (size_t)gy * WW + gx);
            const int c = ci >> 3, o = ci & 7;
            const int s0 = r * SPR + qq * 4;
            ldsu[(c * CH_STRIDE + swz(s0 + 0)) * 8 + o] = to_bf16(v.x);
            ldsu[(c * CH_STRIDE + swz(s0 + 1)) * 8 + o] = to_bf16(v.y);
            ldsu[(c * CH_STRIDE + swz(s0 + 2)) * 8 + o] = to_bf16(v.z);
            ldsu[(c * CH_STRIDE + swz(s0 + 3)) * 8 + o] = to_bf16(v.w);
        }
    }
    // ---- P1b: left halo column (gx = x0-1) -> slot 36 per row ----
    #pragma unroll
    for (int k = 0; k < 2; ++k) {
        const int e = t + 512 * k;
        if (e < 576) {                        // 32 ci x 18 rows
            const int ci = e & 31;
            const int r  = e >> 5;
            const int gy = y0 + r - 1;
            float f = 0.0f;
            if (gy >= 0 && gy < HH && x0 > 0)
                f = fb[(size_t)ci * HW + (size_t)gy * WW + (x0 - 1)];
            const int c = ci >> 3, o = ci & 7;
            ldsu[(c * CH_STRIDE + swz(r * SPR + 36)) * 8 + o] = to_bf16(f);
        }
    }
    __syncthreads();

    // ---- compute: wave w -> row-tiles w and w+8 ----
    const unsigned short* wp = wtb + (size_t)(b * COUT + oc) * 288 + half * 8;
    const int col = oc;                       // output x within tile

    f32x16 acc0, acc1;
    #pragma unroll
    for (int reg = 0; reg < 16; ++reg) { acc0[reg] = 0.0f; acc1[reg] = 0.0f; }

    #pragma unroll
    for (int s = 0; s < 18; ++s) {
        const int tap = s >> 1;               // 0..8
        const int dy  = tap / 3;
        const int dx  = tap % 3;
        const int c   = ((s & 1) << 1) | half;   // 16B chunk (8 ci)
        const short8 af = *reinterpret_cast<const short8*>(wp + s * 16);
        const int xcd = col + dx;
        const int xx  = (xcd == 0) ? 36 : (xcd - 1);   // left halo remap
        {
            const int slot = (w + dy) * SPR + xx;
            const short8 bf = lds[c * CH_STRIDE + swz(slot)];
            acc0 = __builtin_amdgcn_mfma_f32_32x32x16_bf16(af, bf, acc0, 0, 0, 0);
        }
        {
            const int slot = (w + 8 + dy) * SPR + xx;
            const short8 bf = lds[c * CH_STRIDE + swz(slot)];
            acc1 = __builtin_amdgcn_mfma_f32_32x32x16_bf16(af, bf, acc1, 0, 0, 0);
        }
    }

    // C/D layout (verified m74/m101): col = lane&31, row = (reg&3)+8*(reg>>2)+4*half
    {
        const int gy = y0 + w;
        float* op = out + (size_t)(b * COUT) * HW + (size_t)gy * WW + x0 + col;
        #pragma unroll
        for (int reg = 0; reg < 16; ++reg) {
            const int oc_o = (reg & 3) + 8 * (reg >> 2) + 4 * half;
            __builtin_nontemporal_store(acc0[reg], op + (size_t)oc_o * HW);
        }
    }
    {
        const int gy = y0 + w + 8;
        float* op = out + (size_t)(b * COUT) * HW + (size_t)gy * WW + x0 + col;
        #pragma unroll
        for (int reg = 0; reg < 16; ++reg) {
            const int oc_o = (reg & 3) + 8 * (reg >> 2) + 4 * half;
            __builtin_nontemporal_store(acc1[reg], op + (size_t)oc_o * HW);
        }
    }
}

// ---------------------------------------------------------------------------
extern "C" void kernel_launch(void* const* d_in, const int* in_sizes, int n_in,
                              void* d_out, int out_size, void* d_ws, size_t ws_size,
                              hipStream_t stream) {
    const float* fmap       = (const float*)d_in[0];
    const float* mod        = (const float*)d_in[1];
    const float* kernel_mod = (const float*)d_in[2];
    const float* weights    = (const float*)d_in[3];
    float* out = (float*)d_out;
    unsigned short* wtb = (unsigned short*)d_ws;   // [8][32][288] bf16 = 147,456 B

    prep_weights<<<dim3(BATCH * COUT), dim3(320), 0, stream>>>(
        mod, kernel_mod, weights, wtb);

    conv_fused<<<dim3((WW / XW) * (HH / ROWS) * BATCH), dim3(512), 0, stream>>>(
        fmap, wtb, out);
}